// Round 2
// baseline (1259.740 us; speedup 1.0000x reference)
//
#include <hip/hip_runtime.h>

// GRPO fused linear loss: B=4 T=1024 H=2048 V=32000
//   out[0]=loss, out[1..4096]=per_token_logps, out[4097]=mean_kl, out[4098]=clip_ratio
//
// Plan: bf16 MFMA GEMM (x@W^T) fused with online row-LSE partials; exact f32
// token-logit in the finalize pass; scalar GRPO math per token.

typedef unsigned short u16;
typedef __bf16 bf16x8 __attribute__((ext_vector_type(8)));
typedef float f32x4 __attribute__((ext_vector_type(4)));
typedef unsigned short us8 __attribute__((ext_vector_type(8)));

#define BT 4096      // B*T tokens
#define HD 2048      // hidden
#define VO 32000     // vocab
#define MTILES 32    // BT/128
#define NTILES 250   // VO/128
#define NPART 500    // NTILES*2 (two wn-waves per block write separately)

// global -> LDS direct (16B/lane). LDS dest must be wave-uniform base (HW adds lane*16).
#define GLL(gp, lp) __builtin_amdgcn_global_load_lds( \
    (__attribute__((address_space(1))) unsigned int*)(gp), \
    (__attribute__((address_space(3))) unsigned int*)(lp), 16, 0, 0)

__device__ inline u16 f32_to_bf16_rne(float f) {
    unsigned int u = __float_as_uint(f);
    u += 0x7fffu + ((u >> 16) & 1u);
    return (u16)(u >> 16);
}

// ---------------- conversion: f32 -> bf16, 8 elems/thread ----------------
__global__ __launch_bounds__(256) void cvt_bf16(const float* __restrict__ in,
                                                u16* __restrict__ outp, long n8) {
    long i = (long)blockIdx.x * 256 + threadIdx.x;
    if (i >= n8) return;
    const float4* p = (const float4*)in + i * 2;
    float4 a = p[0], b = p[1];
    us8 r;
    r[0] = f32_to_bf16_rne(a.x); r[1] = f32_to_bf16_rne(a.y);
    r[2] = f32_to_bf16_rne(a.z); r[3] = f32_to_bf16_rne(a.w);
    r[4] = f32_to_bf16_rne(b.x); r[5] = f32_to_bf16_rne(b.y);
    r[6] = f32_to_bf16_rne(b.z); r[7] = f32_to_bf16_rne(b.w);
    *(us8*)(outp + i * 8) = r;
}

// ---------------- input_id dtype detector (int64 vs int32 buffer) --------
// If the harness hands us raw int64 (B,T) data, the int32 view has all odd
// indices == 0 (values < 2^31). Checks only the first 4096 int32s (in-bounds
// for both layouts). flag=1 -> treat as int64.
__global__ void detect_i64(const int* __restrict__ ids, int* __restrict__ flag) {
    __shared__ int nz;
    if (threadIdx.x == 0) nz = 0;
    __syncthreads();
    int bad = 0;
    for (int i = 1 + 2 * (int)threadIdx.x; i < 4096; i += 512) bad |= (ids[i] != 0);
    if (bad) atomicOr(&nz, 1);
    __syncthreads();
    if (threadIdx.x == 0) *flag = nz ? 0 : 1;
}

// ---------------- fused GEMM + row-LSE partials (m97 structure) ----------
// 128x128 tile, BK=32, 4 waves (2x2 of 64x64), 16x16x32 bf16 MFMA.
// Epilogue: per-row max & sum(exp) over this block's 64-col wave strip,
// written to partials[row][ntile*2 + wn].
__global__ __launch_bounds__(256) void gemm_lse_partial(
    const u16* __restrict__ xb, const u16* __restrict__ wb,
    const float* __restrict__ bias, float2* __restrict__ partials) {
    __shared__ __align__(16) u16 Al[128 * 32];
    __shared__ __align__(16) u16 Bl[128 * 32];
    const int tid = threadIdx.x;
    const int wid = tid >> 6, lane = tid & 63;
    // mt-fastest: the 32 blocks sharing one W-tile are adjacent in dispatch
    const int mt = blockIdx.x & (MTILES - 1), nt = blockIdx.x >> 5;
    const int m0 = mt * 128, n0 = nt * 128;
    const int wm = (wid >> 1) * 64, wn = (wid & 1) * 64;
    const int fr = lane & 15;            // fragment row/col
    const int fk = (lane >> 4) * 8;      // k sub-offset (elems)

    float bcol[4];
    #pragma unroll
    for (int ni = 0; ni < 4; ++ni) bcol[ni] = bias[n0 + wn + ni * 16 + fr];

    f32x4 acc[4][4] = {};

    // staging: thread t covers row wid*16 + (lane>>2), k-chunk (lane&3)*8 -> lds byte 16*lane
    const int srow = wid * 16 + (lane >> 2);
    const int scol = (lane & 3) * 8;
    const u16* gA = xb + (size_t)(m0 + srow) * HD + scol;
    const u16* gB = wb + (size_t)(n0 + srow) * HD + scol;

    for (int k0 = 0; k0 < HD; k0 += 32) {
        GLL(gA + k0,            &Al[wid * 512]);
        GLL(gA + k0 + 64 * HD,  &Al[2048 + wid * 512]);
        GLL(gB + k0,            &Bl[wid * 512]);
        GLL(gB + k0 + 64 * HD,  &Bl[2048 + wid * 512]);
        __syncthreads();  // compiler emits vmcnt(0) drain before barrier
        bf16x8 af[4], bv[4];
        #pragma unroll
        for (int mi = 0; mi < 4; ++mi)
            af[mi] = *reinterpret_cast<const bf16x8*>(&Al[(wm + mi * 16 + fr) * 32 + fk]);
        #pragma unroll
        for (int ni = 0; ni < 4; ++ni)
            bv[ni] = *reinterpret_cast<const bf16x8*>(&Bl[(wn + ni * 16 + fr) * 32 + fk]);
        #pragma unroll
        for (int mi = 0; mi < 4; ++mi)
            #pragma unroll
            for (int ni = 0; ni < 4; ++ni)
                acc[mi][ni] = __builtin_amdgcn_mfma_f32_16x16x32_bf16(af[mi], bv[ni], acc[mi][ni], 0, 0, 0);
        __syncthreads();
    }

    // epilogue: C/D layout col=lane&15, row=(lane>>4)*4+j  [guide §3, HW-verified]
    const int rgrp = lane >> 4;
    #pragma unroll
    for (int mi = 0; mi < 4; ++mi) {
        #pragma unroll
        for (int j = 0; j < 4; ++j) {
            float vals[4];
            float vmax = -3.4e38f;
            #pragma unroll
            for (int ni = 0; ni < 4; ++ni) {
                vals[ni] = acc[mi][ni][j] + bcol[ni];
                vmax = fmaxf(vmax, vals[ni]);
            }
            #pragma unroll
            for (int s = 1; s < 16; s <<= 1) vmax = fmaxf(vmax, __shfl_xor(vmax, s, 64));
            float se = 0.f;
            #pragma unroll
            for (int ni = 0; ni < 4; ++ni) se += __expf(vals[ni] - vmax);
            #pragma unroll
            for (int s = 1; s < 16; s <<= 1) se += __shfl_xor(se, s, 64);
            if (fr == 0) {
                const int grow = m0 + wm + mi * 16 + rgrp * 4 + j;
                partials[(size_t)grow * NPART + nt * 2 + (wid & 1)] = make_float2(vmax, se);
            }
        }
    }
}

// ---------------- per-token GRPO tail (shared by both paths) -------------
__device__ inline void token_tail(int t, float logps, const int* amask, const float* adv,
                                  const float* ref, const float* old, float* out, float* accum) {
    out[1 + t] = logps;
    const float mf = (float)amask[t];
    const float a  = adv[t >> 10];           // advantage[b], T=1024
    const float d  = ref[t] - logps;
    const float kl = expf(d) - d - 1.f;
    const float c1 = expf(logps - old[t]);
    const float c2 = fminf(fmaxf(c1, 0.8f), 1.2f);
    const float l1 = c1 * a, l2 = c2 * a;
    const float ptl = -(fminf(l1, l2) - 0.04f * kl);
    atomicAdd(accum + 0, ptl * mf);
    atomicAdd(accum + 1, kl * mf);
    atomicAdd(accum + 2, (l1 < l2 ? 1.f : 0.f) * mf);
    atomicAdd(accum + 3, mf);
}

// ---------------- finalize: combine partials, exact f32 token logit ------
__global__ __launch_bounds__(64) void finalize(
    const float* __restrict__ x, const float* __restrict__ w, const float* __restrict__ bias,
    const int* __restrict__ ids, const int* __restrict__ flag, const int* __restrict__ amask,
    const float* __restrict__ adv, const float* __restrict__ ref, const float* __restrict__ old,
    const float2* __restrict__ partials, float* __restrict__ out, float* __restrict__ accum) {
    const int t = blockIdx.x;
    const int lane = threadIdx.x;
    const float2* pp = partials + (size_t)t * NPART;
    float gm = -3.4e38f;
    for (int i = lane; i < NPART; i += 64) gm = fmaxf(gm, pp[i].x);
    for (int s = 32; s; s >>= 1) gm = fmaxf(gm, __shfl_xor(gm, s, 64));
    float gs = 0.f;
    for (int i = lane; i < NPART; i += 64) { float2 p = pp[i]; gs += p.y * __expf(p.x - gm); }
    for (int s = 32; s; s >>= 1) gs += __shfl_xor(gs, s, 64);
    const float lse = gm + logf(gs);
    const int id = (*flag) ? ids[2 * t] : ids[t];
    const float* xr = x + (size_t)t * HD;
    const float* wr = w + (size_t)id * HD;
    float dot = 0.f;
    for (int h = lane; h < HD; h += 64) dot = fmaf(xr[h], wr[h], dot);
    for (int s = 32; s; s >>= 1) dot += __shfl_xor(dot, s, 64);
    if (lane == 0) token_tail(t, (dot + bias[id]) - lse, amask, adv, ref, old, out, accum);
}

// ---------------- scalars ------------------------------------------------
__global__ void final_scalars(const float* __restrict__ accum, float* __restrict__ out) {
    const float ms = accum[3];
    out[0]    = accum[0] / ms;
    out[4097] = accum[1] / ms;
    out[4098] = accum[2] / ms;
}

// ---------------- fallback (ws too small): all-f32, exact ----------------
__global__ __launch_bounds__(256) void naive_token(
    const float* __restrict__ x, const float* __restrict__ w, const float* __restrict__ bias,
    const int* __restrict__ ids, const int* __restrict__ flag, const int* __restrict__ amask,
    const float* __restrict__ adv, const float* __restrict__ ref, const float* __restrict__ old,
    float* __restrict__ out, float* __restrict__ accum) {
    __shared__ float xl[HD];
    __shared__ float wm_[4], ws_[4], wt_[4];
    const int t = blockIdx.x, tid = threadIdx.x, wid = tid >> 6, lane = tid & 63;
    for (int i = tid; i < HD; i += 256) xl[i] = x[(size_t)t * HD + i];
    const int id = (*flag) ? ids[2 * t] : ids[t];
    __syncthreads();
    float m = -3.4e38f, s = 0.f, tok = 0.f;
    for (int v = wid; v < VO; v += 4) {
        const float* wr = w + (size_t)v * HD;
        float d = 0.f;
        for (int h = lane; h < HD; h += 64) d = fmaf(xl[h], wr[h], d);
        for (int o = 32; o; o >>= 1) d += __shfl_xor(d, o, 64);
        d += bias[v];
        if (v == id) tok = d;
        const float nm = fmaxf(m, d);
        s = s * __expf(m - nm) + __expf(d - nm);
        m = nm;
    }
    if (lane == 0) { wm_[wid] = m; ws_[wid] = s; wt_[wid] = tok; }
    __syncthreads();
    if (tid == 0) {
        float gm = fmaxf(fmaxf(wm_[0], wm_[1]), fmaxf(wm_[2], wm_[3]));
        float gs = 0.f, tk = 0.f;
        for (int i = 0; i < 4; ++i) { gs += ws_[i] * __expf(wm_[i] - gm); tk += wt_[i]; }
        const float lse = gm + logf(gs);
        token_tail(t, tk - lse, amask, adv, ref, old, out, accum);
    }
}

// ---------------- host ---------------------------------------------------
extern "C" void kernel_launch(void* const* d_in, const int* in_sizes, int n_in,
                              void* d_out, int out_size, void* d_ws, size_t ws_size,
                              hipStream_t stream) {
    const float* x     = (const float*)d_in[0];
    const float* w     = (const float*)d_in[1];
    const float* bias  = (const float*)d_in[2];
    const int*   ids   = (const int*)d_in[3];
    const int*   amask = (const int*)d_in[4];
    const float* adv   = (const float*)d_in[5];
    const float* ref   = (const float*)d_in[6];
    const float* old   = (const float*)d_in[7];
    float* out = (float*)d_out;

    char* ws = (char*)d_ws;
    float* accum = (float*)ws;          // 4 floats
    int*   flag  = (int*)(ws + 16);
    const size_t off      = 256;
    const size_t xb_bytes = (size_t)BT * HD * 2;        // 16.8 MB
    const size_t wb_bytes = (size_t)VO * HD * 2;        // 131 MB
    const size_t pt_bytes = (size_t)BT * NPART * 8;     // 16.4 MB
    const bool fast = ws_size >= off + xb_bytes + wb_bytes + pt_bytes;

    hipMemsetAsync(accum, 0, 16, stream);
    detect_i64<<<1, 256, 0, stream>>>(ids, flag);

    if (fast) {
        u16* xb = (u16*)(ws + off);
        u16* wb = (u16*)(ws + off + xb_bytes);
        float2* partials = (float2*)(ws + off + xb_bytes + wb_bytes);
        const long nx8 = (long)BT * HD / 8, nw8 = (long)VO * HD / 8;
        cvt_bf16<<<(int)((nx8 + 255) / 256), 256, 0, stream>>>(x, xb, nx8);
        cvt_bf16<<<(int)((nw8 + 255) / 256), 256, 0, stream>>>(w, wb, nw8);
        gemm_lse_partial<<<MTILES * NTILES, 256, 0, stream>>>(xb, wb, bias, partials);
        finalize<<<BT, 64, 0, stream>>>(x, w, bias, ids, flag, amask, adv, ref, old,
                                        partials, out, accum);
    } else {
        naive_token<<<BT, 256, 0, stream>>>(x, w, bias, ids, flag, amask, adv, ref, old,
                                            out, accum);
    }
    final_scalars<<<1, 1, 0, stream>>>(accum, out);
}

// Round 4
// 1125.283 us; speedup vs baseline: 1.1195x; 1.1195x over previous
//
#include <hip/hip_runtime.h>

// GRPO fused linear loss: B=4 T=1024 H=2048 V=32000
//   out[0]=loss, out[1..4096]=per_token_logps, out[4097]=mean_kl, out[4098]=clip_ratio
//
// R4 == R3 (never executed: GPU acquisition timeout), re-audited:
// 256x256 8-phase GEMM template (T1 XCD-swizzle, T2 LDS XOR-swizzle, T3+T4
// 8-phase counted-vmcnt pipeline, T5 setprio) with fused row-LSE epilogue.

typedef unsigned short u16;
typedef __bf16 bf16x8 __attribute__((ext_vector_type(8)));
typedef float f32x4 __attribute__((ext_vector_type(4)));
typedef unsigned short us8 __attribute__((ext_vector_type(8)));

#define BT 4096      // B*T tokens
#define HD 2048      // hidden
#define VO 32000     // vocab
#define MT2 16       // BT/256
#define NT2 125      // VO/256
#define NPART 500    // NT2*4 wn-strips
#define KT 32        // HD/64 K-tiles

// global -> LDS direct (16B/lane). LDS dest wave-uniform base + lane*16.
#define GLL(gp, lp) __builtin_amdgcn_global_load_lds( \
    (__attribute__((address_space(1))) unsigned int*)(gp), \
    (__attribute__((address_space(3))) unsigned int*)(lp), 16, 0, 0)

__device__ inline u16 f32_to_bf16_rne(float f) {
    unsigned int u = __float_as_uint(f);
    u += 0x7fffu + ((u >> 16) & 1u);
    return (u16)(u >> 16);
}

// ---------------- conversion: f32 -> bf16, 8 elems/thread ----------------
__global__ __launch_bounds__(256) void cvt_bf16(const float* __restrict__ in,
                                                u16* __restrict__ outp, long n8) {
    long i = (long)blockIdx.x * 256 + threadIdx.x;
    if (i >= n8) return;
    const float4* p = (const float4*)in + i * 2;
    float4 a = p[0], b = p[1];
    us8 r;
    r[0] = f32_to_bf16_rne(a.x); r[1] = f32_to_bf16_rne(a.y);
    r[2] = f32_to_bf16_rne(a.z); r[3] = f32_to_bf16_rne(a.w);
    r[4] = f32_to_bf16_rne(b.x); r[5] = f32_to_bf16_rne(b.y);
    r[6] = f32_to_bf16_rne(b.z); r[7] = f32_to_bf16_rne(b.w);
    *(us8*)(outp + i * 8) = r;
}

// ---------------- input_id dtype detector (int64 vs int32 buffer) --------
__global__ void detect_i64(const int* __restrict__ ids, int* __restrict__ flag) {
    __shared__ int nz;
    if (threadIdx.x == 0) nz = 0;
    __syncthreads();
    int bad = 0;
    for (int i = 1 + 2 * (int)threadIdx.x; i < 4096; i += 512) bad |= (ids[i] != 0);
    if (bad) atomicOr(&nz, 1);
    __syncthreads();
    if (threadIdx.x == 0) *flag = nz ? 0 : 1;
}

// ---------------- 256x256 8-phase GEMM + row-LSE partials ----------------
// 8 waves = 2(wm) x 4(wn); per-wave output 128x64; BK=64 (kk=0,1).
// LDS 128KB: [buf][A/B][half 128-rows][row 128B swizzled].
// Swizzle: byte c' = c ^ ((row&7)<<4); GLL source pre-inverse-swizzled.
__global__ __launch_bounds__(512, 2) void gemm256_lse(
    const u16* __restrict__ xb, const u16* __restrict__ wb,
    const float* __restrict__ bias, float2* __restrict__ partials) {
    __shared__ __align__(16) char L[131072];
    const int tid = threadIdx.x;
    const int wid = tid >> 6, lane = tid & 63;
    // T1: bijective XCD swizzle (2000 % 8 == 0), then mt-fastest decompose
    const int b0 = blockIdx.x;
    const int swz = (b0 & 7) * 250 + (b0 >> 3);
    const int mt = swz & 15, nt = swz >> 4;
    const int m0 = mt * 256, n0 = nt * 256;
    const int wm = wid >> 2, wn = wid & 3;
    const int fr = lane & 15, q4 = lane >> 4;
    const int cs = (fr & 7) << 4;
    const int cb[2] = { (q4 * 16) ^ cs, (64 + q4 * 16) ^ cs };
    // staging constants: lane covers row (wid*8 + lane>>3), slot lane&7
    const int sl = lane >> 3, ss = lane & 7;
    const int swze = (ss ^ sl) << 3;          // inverse-swizzled source col (elems)
    const int srow = wid * 8 + sl;
    const int abase = wm * 16384;             // this wave's A half
    const int bbase = 32768 + (wn >> 1) * 16384;
    const int brow0 = (wn & 1) * 64;

    f32x4 acc[8][4] = {};
    bf16x8 bfr[4];

    // stage half-tile h: K-tile h>>2 into buf (h>>2)&1; j: 0=A0 1=A1 2=B0 3=B1
    auto STAGE = [&](int h) {
        const int th = h >> 2, j = h & 3, ab = j >> 1, hf = j & 1, bu = th & 1;
        const u16* gp = ab ? wb : xb;
        const int gb = (ab ? n0 : m0) + hf * 128;
        char* dst = L + bu * 65536 + ab * 32768 + hf * 16384 + wid * 1024;
        #pragma unroll
        for (int r = 0; r < 2; ++r) {
            const u16* src = gp + (size_t)(gb + r * 64 + srow) * HD + th * 64 + swze;
            GLL(src, dst + r * 8192);
        }
    };

    // prologue: K-tile0 (4 halves) + 3 halves of K-tile1; 3-deep steady state
    STAGE(0); STAGE(1); STAGE(2); STAGE(3);
    asm volatile("s_waitcnt vmcnt(4)" ::: "memory");
    STAGE(4); STAGE(5); STAGE(6);
    asm volatile("s_waitcnt vmcnt(6)" ::: "memory");
    __builtin_amdgcn_s_barrier();
    __builtin_amdgcn_sched_barrier(0);

    for (int t = 0; t < KT; ++t) {
        const int buf = (t & 1) * 65536;
        #pragma unroll
        for (int q = 0; q < 4; ++q) {
            const int kk = q >> 1, mh = q & 1;
            bf16x8 afr[4];
            #pragma unroll
            for (int mm = 0; mm < 4; ++mm)
                afr[mm] = *(const bf16x8*)(L + buf + abase +
                    ((mh * 4 + mm) * 16 + fr) * 128 + cb[kk]);
            if (q == 0 || q == 2) {
                #pragma unroll
                for (int n = 0; n < 4; ++n)
                    bfr[n] = *(const bf16x8*)(L + buf + bbase +
                        (brow0 + n * 16 + fr) * 128 + cb[kk]);
            }
            const int h = 7 + 4 * t + q;
            if (h < 4 * KT) STAGE(h);
            __builtin_amdgcn_s_barrier();
            asm volatile("s_waitcnt lgkmcnt(0)" ::: "memory");
            __builtin_amdgcn_sched_barrier(0);      // rule #18: pin MFMA below wait
            __builtin_amdgcn_s_setprio(1);
            #pragma unroll
            for (int mm = 0; mm < 4; ++mm)
                #pragma unroll
                for (int n = 0; n < 4; ++n)
                    acc[mh * 4 + mm][n] = __builtin_amdgcn_mfma_f32_16x16x32_bf16(
                        afr[mm], bfr[n], acc[mh * 4 + mm][n], 0, 0, 0);
            __builtin_amdgcn_s_setprio(0);
            if (q == 3) {
                if (t < KT - 2)       asm volatile("s_waitcnt vmcnt(6)" ::: "memory");
                else if (t == KT - 2) asm volatile("s_waitcnt vmcnt(0)" ::: "memory");
            }
            __builtin_amdgcn_s_barrier();
            __builtin_amdgcn_sched_barrier(0);
        }
    }

    // epilogue: per-row (max, sum-exp) over this wave's 64-col strip
    float bcol[4];
    #pragma unroll
    for (int n = 0; n < 4; ++n) bcol[n] = bias[n0 + wn * 64 + n * 16 + fr];
    const int rgrp = lane >> 4;
    #pragma unroll
    for (int m = 0; m < 8; ++m) {
        #pragma unroll
        for (int j = 0; j < 4; ++j) {
            float vals[4];
            float vmax = -3.4e38f;
            #pragma unroll
            for (int n = 0; n < 4; ++n) {
                vals[n] = acc[m][n][j] + bcol[n];
                vmax = fmaxf(vmax, vals[n]);
            }
            #pragma unroll
            for (int s = 1; s < 16; s <<= 1) vmax = fmaxf(vmax, __shfl_xor(vmax, s, 64));
            float se = 0.f;
            #pragma unroll
            for (int n = 0; n < 4; ++n) se += __expf(vals[n] - vmax);
            #pragma unroll
            for (int s = 1; s < 16; s <<= 1) se += __shfl_xor(se, s, 64);
            if (fr == 0) {
                const int grow = m0 + wm * 128 + m * 16 + rgrp * 4 + j;
                partials[(size_t)grow * NPART + nt * 4 + wn] = make_float2(vmax, se);
            }
        }
    }
}

// ---------------- per-token GRPO tail ------------------------------------
__device__ inline void token_tail(int t, float logps, const int* amask, const float* adv,
                                  const float* ref, const float* old, float* out, float* accum) {
    out[1 + t] = logps;
    const float mf = (float)amask[t];
    const float a  = adv[t >> 10];
    const float d  = ref[t] - logps;
    const float kl = expf(d) - d - 1.f;
    const float c1 = expf(logps - old[t]);
    const float c2 = fminf(fmaxf(c1, 0.8f), 1.2f);
    const float l1 = c1 * a, l2 = c2 * a;
    const float ptl = -(fminf(l1, l2) - 0.04f * kl);
    atomicAdd(accum + 0, ptl * mf);
    atomicAdd(accum + 1, kl * mf);
    atomicAdd(accum + 2, (l1 < l2 ? 1.f : 0.f) * mf);
    atomicAdd(accum + 3, mf);
}

// ---------------- finalize: combine partials, exact f32 token logit ------
__global__ __launch_bounds__(64) void finalize(
    const float* __restrict__ x, const float* __restrict__ w, const float* __restrict__ bias,
    const int* __restrict__ ids, const int* __restrict__ flag, const int* __restrict__ amask,
    const float* __restrict__ adv, const float* __restrict__ ref, const float* __restrict__ old,
    const float2* __restrict__ partials, float* __restrict__ out, float* __restrict__ accum) {
    const int t = blockIdx.x;
    const int lane = threadIdx.x;
    const float2* pp = partials + (size_t)t * NPART;
    float gm = -3.4e38f;
    for (int i = lane; i < NPART; i += 64) gm = fmaxf(gm, pp[i].x);
    for (int s = 32; s; s >>= 1) gm = fmaxf(gm, __shfl_xor(gm, s, 64));
    float gs = 0.f;
    for (int i = lane; i < NPART; i += 64) { float2 p = pp[i]; gs += p.y * __expf(p.x - gm); }
    for (int s = 32; s; s >>= 1) gs += __shfl_xor(gs, s, 64);
    const float lse = gm + logf(gs);
    const int id = (*flag) ? ids[2 * t] : ids[t];
    const float4* xr = (const float4*)(x + (size_t)t * HD);
    const float4* wr = (const float4*)(w + (size_t)id * HD);
    float dot = 0.f;
    for (int i = lane; i < HD / 4; i += 64) {
        float4 a = xr[i], c = wr[i];
        dot = fmaf(a.x, c.x, fmaf(a.y, c.y, fmaf(a.z, c.z, fmaf(a.w, c.w, dot))));
    }
    for (int s = 32; s; s >>= 1) dot += __shfl_xor(dot, s, 64);
    if (lane == 0) token_tail(t, (dot + bias[id]) - lse, amask, adv, ref, old, out, accum);
}

// ---------------- scalars ------------------------------------------------
__global__ void final_scalars(const float* __restrict__ accum, float* __restrict__ out) {
    const float ms = accum[3];
    out[0]    = accum[0] / ms;
    out[4097] = accum[1] / ms;
    out[4098] = accum[2] / ms;
}

// ---------------- fallback (ws too small): all-f32, exact ----------------
__global__ __launch_bounds__(256) void naive_token(
    const float* __restrict__ x, const float* __restrict__ w, const float* __restrict__ bias,
    const int* __restrict__ ids, const int* __restrict__ flag, const int* __restrict__ amask,
    const float* __restrict__ adv, const float* __restrict__ ref, const float* __restrict__ old,
    float* __restrict__ out, float* __restrict__ accum) {
    __shared__ float xl[HD];
    __shared__ float wm_[4], ws_[4], wt_[4];
    const int t = blockIdx.x, tid = threadIdx.x, wid = tid >> 6, lane = tid & 63;
    for (int i = tid; i < HD; i += 256) xl[i] = x[(size_t)t * HD + i];
    const int id = (*flag) ? ids[2 * t] : ids[t];
    __syncthreads();
    float m = -3.4e38f, s = 0.f, tok = 0.f;
    for (int v = wid; v < VO; v += 4) {
        const float* wr = w + (size_t)v * HD;
        float d = 0.f;
        for (int h = lane; h < HD; h += 64) d = fmaf(xl[h], wr[h], d);
        for (int o = 32; o; o >>= 1) d += __shfl_xor(d, o, 64);
        d += bias[v];
        if (v == id) tok = d;
        const float nm = fmaxf(m, d);
        s = s * __expf(m - nm) + __expf(d - nm);
        m = nm;
    }
    if (lane == 0) { wm_[wid] = m; ws_[wid] = s; wt_[wid] = tok; }
    __syncthreads();
    if (tid == 0) {
        float gm = fmaxf(fmaxf(wm_[0], wm_[1]), fmaxf(wm_[2], wm_[3]));
        float gs = 0.f, tk = 0.f;
        for (int i = 0; i < 4; ++i) { gs += ws_[i] * __expf(wm_[i] - gm); tk += wt_[i]; }
        const float lse = gm + logf(gs);
        token_tail(t, tk - lse, amask, adv, ref, old, out, accum);
    }
}

// ---------------- host ---------------------------------------------------
extern "C" void kernel_launch(void* const* d_in, const int* in_sizes, int n_in,
                              void* d_out, int out_size, void* d_ws, size_t ws_size,
                              hipStream_t stream) {
    const float* x     = (const float*)d_in[0];
    const float* w     = (const float*)d_in[1];
    const float* bias  = (const float*)d_in[2];
    const int*   ids   = (const int*)d_in[3];
    const int*   amask = (const int*)d_in[4];
    const float* adv   = (const float*)d_in[5];
    const float* ref   = (const float*)d_in[6];
    const float* old   = (const float*)d_in[7];
    float* out = (float*)d_out;

    char* ws = (char*)d_ws;
    float* accum = (float*)ws;          // 4 floats
    int*   flag  = (int*)(ws + 16);
    const size_t off      = 256;
    const size_t xb_bytes = (size_t)BT * HD * 2;        // 16.8 MB
    const size_t wb_bytes = (size_t)VO * HD * 2;        // 131 MB
    const size_t pt_bytes = (size_t)BT * NPART * 8;     // 16.4 MB
    const bool fast = ws_size >= off + xb_bytes + wb_bytes + pt_bytes;

    hipMemsetAsync(accum, 0, 16, stream);
    detect_i64<<<1, 256, 0, stream>>>(ids, flag);

    if (fast) {
        u16* xb = (u16*)(ws + off);
        u16* wb = (u16*)(ws + off + xb_bytes);
        float2* partials = (float2*)(ws + off + xb_bytes + wb_bytes);
        const long nx8 = (long)BT * HD / 8, nw8 = (long)VO * HD / 8;
        cvt_bf16<<<(int)((nx8 + 255) / 256), 256, 0, stream>>>(x, xb, nx8);
        cvt_bf16<<<(int)((nw8 + 255) / 256), 256, 0, stream>>>(w, wb, nw8);
        gemm256_lse<<<MT2 * NT2, 512, 0, stream>>>(xb, wb, bias, partials);
        finalize<<<BT, 64, 0, stream>>>(x, w, bias, ids, flag, amask, adv, ref, old,
                                        partials, out, accum);
    } else {
        naive_token<<<BT, 256, 0, stream>>>(x, w, bias, ids, flag, amask, adv, ref, old,
                                            out, accum);
    }
    final_scalars<<<1, 1, 0, stream>>>(accum, out);
}